// Round 3
// baseline (168.655 us; speedup 1.0000x reference)
//
#include <hip/hip_runtime.h>
#include <hip/hip_bf16.h>

#define N_NODES 50000
#define N_EDGES 800000
#define DIM     128
#define N_STRIPS (N_NODES / 16)               // 3125 exact: 16-row strips
#define N_BKT    782                          // bucket = dst >> 6 (64 nodes/bucket)
#define CHUNK_E  8192                         // edges per scatter chunk
#define EDGE_CHUNKS ((N_EDGES + CHUNK_E - 1) / CHUNK_E)  // 98 (last 5376)
#define BCAP     1536                         // global bucket region cap (mean 1024, 16 sigma)
#define EBUF_CAP 1408                         // LDS sorted-edge cap (mean 1024, 12 sigma)
#define GEMM_BLOCKS ((N_STRIPS + 3) / 4)      // 782
#define FRONT_BLOCKS (EDGE_CHUNKS + GEMM_BLOCKS) // 880
#define SUP_ROWS 50048                        // support rows incl. tail-strip slack

typedef short short8 __attribute__((ext_vector_type(8)));
typedef float floatx4 __attribute__((ext_vector_type(4)));

// fp32 -> bf16 (RNE) bit pattern
__device__ inline unsigned short f2bf(float f) {
    __hip_bfloat16 h = __float2bfloat16(f);
    return *reinterpret_cast<unsigned short*>(&h);
}

__device__ inline uint4 pack8_relu(const float a[8]) {
    uint4 o;
    o.x = (unsigned)f2bf(fmaxf(a[0],0.f)) | ((unsigned)f2bf(fmaxf(a[1],0.f)) << 16);
    o.y = (unsigned)f2bf(fmaxf(a[2],0.f)) | ((unsigned)f2bf(fmaxf(a[3],0.f)) << 16);
    o.z = (unsigned)f2bf(fmaxf(a[4],0.f)) | ((unsigned)f2bf(fmaxf(a[5],0.f)) << 16);
    o.w = (unsigned)f2bf(fmaxf(a[6],0.f)) | ((unsigned)f2bf(fmaxf(a[7],0.f)) << 16);
    return o;
}

// ---------------------------------------------------------------------------
// Dispatch 1: pack W1 (blocks 0-7) and W2 (blocks 8-15) into MFMA B-fragment
// order; block 16 zeroes the global bucket counters.
// slot s=(ks*8+nt)*64+lane holds 8 bf16: B[ks*32+(lane>>4)*8+j][nt*16+(lane&15)]
// ---------------------------------------------------------------------------
__global__ __launch_bounds__(256) void pre_pack(
    const float* __restrict__ W1, const float* __restrict__ W2,
    uint4* __restrict__ p1, uint4* __restrict__ p2, int* __restrict__ bcnt)
{
    const int blk = blockIdx.x;
    const int t   = threadIdx.x;
    if (blk < 8) {
        const int s    = blk * 256 + t;                  // 0..2047
        const int lane = s & 63;
        const int nt   = (s >> 6) & 7;
        const int ks   = s >> 9;
        const int m    = lane & 15;
        const int q    = lane >> 4;
        unsigned short e[8];
        #pragma unroll
        for (int j = 0; j < 8; ++j)
            e[j] = f2bf(W1[(ks * 32 + q * 8 + j) * DIM + nt * 16 + m]);
        uint4 o;
        o.x = (unsigned)e[0] | ((unsigned)e[1] << 16);
        o.y = (unsigned)e[2] | ((unsigned)e[3] << 16);
        o.z = (unsigned)e[4] | ((unsigned)e[5] << 16);
        o.w = (unsigned)e[6] | ((unsigned)e[7] << 16);
        p1[s] = o;
    } else if (blk < 16) {
        // B[k][n] = W2[n][k]  (x @ W2^T)
        const int s    = (blk - 8) * 256 + t;
        const int lane = s & 63;
        const int nt   = (s >> 6) & 7;
        const int ks   = s >> 9;
        const int m    = lane & 15;
        const int q    = lane >> 4;
        const float4 f0 = *reinterpret_cast<const float4*>(&W2[(nt * 16 + m) * DIM + ks * 32 + q * 8]);
        const float4 f1 = *reinterpret_cast<const float4*>(&W2[(nt * 16 + m) * DIM + ks * 32 + q * 8 + 4]);
        unsigned short e[8];
        e[0] = f2bf(f0.x); e[1] = f2bf(f0.y); e[2] = f2bf(f0.z); e[3] = f2bf(f0.w);
        e[4] = f2bf(f1.x); e[5] = f2bf(f1.y); e[6] = f2bf(f1.z); e[7] = f2bf(f1.w);
        uint4 o;
        o.x = (unsigned)e[0] | ((unsigned)e[1] << 16);
        o.y = (unsigned)e[2] | ((unsigned)e[3] << 16);
        o.z = (unsigned)e[4] | ((unsigned)e[5] << 16);
        o.w = (unsigned)e[6] | ((unsigned)e[7] << 16);
        p2[s] = o;
    } else {
        for (int i = t; i < 800; i += 256) bcnt[i] = 0;  // 782 used
    }
}

// ---------------------------------------------------------------------------
// Dispatch 2: bucket scatter (blocks [0,98)) co-scheduled with GEMM1
// (blocks [98,880)). Scatter: 8192-edge chunks -> per-(chunk,bucket) runs
// avg 10.5 edges (~84 B) so bucketed writes are ~line-sized. GEMM1 stages
// its 64x128 bf16 tile in LDS and writes coalesced uint4 (was 2-B stores).
// ---------------------------------------------------------------------------
__global__ __launch_bounds__(256) void front(
    const float* __restrict__ x, const float* __restrict__ bias,
    const int* __restrict__ src, const int* __restrict__ dst,
    const float* __restrict__ vals, const uint4* __restrict__ p1,
    unsigned short* __restrict__ support, int* __restrict__ bcnt,
    int2* __restrict__ bucketed)
{
    __shared__ int bh[800];
    __shared__ int rcur[800];
    __shared__ unsigned short stg[64 * 136];   // pad 136: aligned uint4 rows, spread banks
    const int t = threadIdx.x;

    if (blockIdx.x < EDGE_CHUNKS) {
        // ---------------- bucket scatter via atomic range reservation -------
        const int chunk = blockIdx.x;
        for (int i = t; i < 800; i += 256) bh[i] = 0;
        __syncthreads();
        const int base   = chunk * CHUNK_E;
        const int navail = min(CHUNK_E, N_EDGES - base); // %4==0
        const int4* d4 = reinterpret_cast<const int4*>(dst + base);
        #pragma unroll
        for (int i = 0; i < 8; ++i) {
            const int j = t + i * 256;
            if (j * 4 < navail) {
                const int4 d = d4[j];
                atomicAdd(&bh[d.x >> 6], 1);
                atomicAdd(&bh[d.y >> 6], 1);
                atomicAdd(&bh[d.z >> 6], 1);
                atomicAdd(&bh[d.w >> 6], 1);
            }
        }
        __syncthreads();
        for (int b = t; b < N_BKT; b += 256)
            rcur[b] = b * BCAP + atomicAdd(&bcnt[b], bh[b]);
        __syncthreads();
        const int4*   s4 = reinterpret_cast<const int4*>(src + base);
        const float4* v4 = reinterpret_cast<const float4*>(vals + base);
        #pragma unroll
        for (int i = 0; i < 8; ++i) {
            const int j = t + i * 256;
            if (j * 4 < navail) {
                const int4   s = s4[j];
                const int4   d = d4[j];
                const float4 v = v4[j];
                int p;
                p = atomicAdd(&rcur[d.x >> 6], 1);
                bucketed[p] = make_int2((s.x & 0xFFFF) | ((d.x & 63) << 16), __float_as_int(v.x));
                p = atomicAdd(&rcur[d.y >> 6], 1);
                bucketed[p] = make_int2((s.y & 0xFFFF) | ((d.y & 63) << 16), __float_as_int(v.y));
                p = atomicAdd(&rcur[d.z >> 6], 1);
                bucketed[p] = make_int2((s.z & 0xFFFF) | ((d.z & 63) << 16), __float_as_int(v.z));
                p = atomicAdd(&rcur[d.w >> 6], 1);
                bucketed[p] = make_int2((s.w & 0xFFFF) | ((d.w & 63) << 16), __float_as_int(v.w));
            }
        }
    } else {
        // ---------------- GEMM1: support = bf16(x @ W1 + b) ----------------
        const int gb    = blockIdx.x - EDGE_CHUNKS;      // 0..781
        const int wave  = t >> 6;
        const int lane  = t & 63;
        const int strip = gb * 4 + wave;
        const int m = lane & 15;
        const int q = lane >> 4;
        const bool valid = strip < N_STRIPS;             // block 781 waves 1-3 idle

        if (valid) {
            const int row = strip * 16 + m;
            short8 a[4];
            const float4* xr = reinterpret_cast<const float4*>(&x[(size_t)row * DIM]);
            #pragma unroll
            for (int ks = 0; ks < 4; ++ks) {
                const float4 f0 = xr[ks * 8 + q * 2];
                const float4 f1 = xr[ks * 8 + q * 2 + 1];
                short8 tt;
                tt[0] = (short)f2bf(f0.x); tt[1] = (short)f2bf(f0.y);
                tt[2] = (short)f2bf(f0.z); tt[3] = (short)f2bf(f0.w);
                tt[4] = (short)f2bf(f1.x); tt[5] = (short)f2bf(f1.y);
                tt[6] = (short)f2bf(f1.z); tt[7] = (short)f2bf(f1.w);
                a[ks] = tt;
            }

            floatx4 acc[8];
            #pragma unroll
            for (int nt = 0; nt < 8; ++nt) { acc[nt][0]=0.f; acc[nt][1]=0.f; acc[nt][2]=0.f; acc[nt][3]=0.f; }

            const short8* Bp = (const short8*)p1;
            #pragma unroll
            for (int ks = 0; ks < 4; ++ks) {
                #pragma unroll
                for (int nt = 0; nt < 8; ++nt) {
                    const short8 bf = Bp[(ks * 8 + nt) * 64 + lane];
                    acc[nt] = __builtin_amdgcn_mfma_f32_16x16x32_bf16(a[ks], bf, acc[nt], 0, 0, 0);
                }
            }

            #pragma unroll
            for (int nt = 0; nt < 8; ++nt) {
                const float bb = bias[nt * 16 + m];
                #pragma unroll
                for (int i = 0; i < 4; ++i)
                    stg[(wave * 16 + q * 4 + i) * 136 + nt * 16 + m] = f2bf(acc[nt][i] + bb);
            }
        }
        __syncthreads();
        // coalesced writeout: 64 rows x 256 B = 1024 uint4 chunks, 4/thread.
        // rows for strips >= N_STRIPS write garbage into the slack region
        // (SUP_ROWS) and are never read (src < 50000).
        const size_t rbase = (size_t)gb * 64;
        #pragma unroll
        for (int k = 0; k < 4; ++k) {
            const int chunk2 = t + k * 256;
            const int lrow  = chunk2 >> 4;
            const int piece = chunk2 & 15;
            const uint4 v = *reinterpret_cast<const uint4*>(&stg[lrow * 136 + piece * 8]);
            *reinterpret_cast<uint4*>(&support[(rbase + lrow) * DIM + piece * 8]) = v;
        }
    }
}

// ---------------------------------------------------------------------------
// Gather pass 1: dims 0-63 only. Per 64-node bucket: counting-sort edges into
// LDS, then 2-node-interleaved gather (8 edges/instr, 128 B rows) so the
// chip-wide hot set is 6.4 MB (65% fits per-XCD L2). Writes bf16 agg half to
// global. Pass 2 (next kernel) does dims 64-127 + fused GEMM2.
// ---------------------------------------------------------------------------
__global__ __launch_bounds__(256) void gather_h0(
    const unsigned int* __restrict__ sup, const int2* __restrict__ bucketed,
    const int* __restrict__ bcnt, unsigned int* __restrict__ aggG)
{
    __shared__ int2 ebuf[EBUF_CAP];
    __shared__ int cnt[64];
    __shared__ int coff[64];
    __shared__ int cur[64];

    const int b = blockIdx.x;
    const int t = threadIdx.x;
    int nE = bcnt[b];
    if (nE > EBUF_CAP) nE = EBUF_CAP;
    const int base = b * BCAP;

    // ---- counting sort by dst&63 into ebuf ----
    if (t < 64) cnt[t] = 0;
    __syncthreads();
    for (int i = t; i < nE; i += 256)
        atomicAdd(&cnt[(bucketed[base + i].x >> 16) & 63], 1);
    __syncthreads();
    if (t < 64) coff[t] = cnt[t];
    __syncthreads();
    for (int off = 1; off < 64; off <<= 1) {
        int u = 0;
        if (t < 64 && t >= off) u = coff[t - off];
        __syncthreads();
        if (t < 64 && t >= off) coff[t] += u;
        __syncthreads();
    }
    if (t < 64) cur[t] = coff[t] - cnt[t];
    __syncthreads();
    for (int i = t; i < nE; i += 256) {
        const int2 e = bucketed[base + i];
        const int  n = (e.x >> 16) & 63;
        const int  p = atomicAdd(&cur[n], 1);
        ebuf[p] = e;
    }
    __syncthreads();

    // ---- gather dims 0-63: wave w -> nodes w*16..+16, pairs (j, j+8) ----
    const int w = t >> 6, lane = t & 63;
    const int g = lane >> 3, dl = lane & 7;   // 8 edges/instr, 8 dims/lane
    for (int j = 0; j < 8; ++j) {
        const int nA = w * 16 + j, nB = nA + 8;
        const int endA = cur[nA], cA = cnt[nA], begA = endA - cA;
        const int endB = cur[nB], cB = cnt[nB], begB = endB - cB;
        float aA[8] = {0.f,0.f,0.f,0.f,0.f,0.f,0.f,0.f};
        float aB[8] = {0.f,0.f,0.f,0.f,0.f,0.f,0.f,0.f};
        const int nI = max((cA + 7) >> 3, (cB + 7) >> 3);
        #pragma unroll 2
        for (int it = 0; it < nI; ++it) {
            const int iA = begA + it * 8 + g;
            const int iB = begB + it * 8 + g;
            const bool vA = iA < endA, vB = iB < endB;
            const int2 eA = ebuf[vA ? iA : 0];
            const int2 eB = ebuf[vB ? iB : 0];
            const float valA = vA ? __int_as_float(eA.y) : 0.f;
            const float valB = vB ? __int_as_float(eB.y) : 0.f;
            const int sA = vA ? (eA.x & 0xFFFF) : 0;   // row 0: finite, x0
            const int sB = vB ? (eB.x & 0xFFFF) : 0;
            const uint4 uA = *reinterpret_cast<const uint4*>(&sup[(size_t)sA * 64 + dl * 4]);
            const uint4 uB = *reinterpret_cast<const uint4*>(&sup[(size_t)sB * 64 + dl * 4]);
            aA[0] += __uint_as_float(uA.x << 16)         * valA;
            aA[1] += __uint_as_float(uA.x & 0xffff0000u) * valA;
            aA[2] += __uint_as_float(uA.y << 16)         * valA;
            aA[3] += __uint_as_float(uA.y & 0xffff0000u) * valA;
            aA[4] += __uint_as_float(uA.z << 16)         * valA;
            aA[5] += __uint_as_float(uA.z & 0xffff0000u) * valA;
            aA[6] += __uint_as_float(uA.w << 16)         * valA;
            aA[7] += __uint_as_float(uA.w & 0xffff0000u) * valA;
            aB[0] += __uint_as_float(uB.x << 16)         * valB;
            aB[1] += __uint_as_float(uB.x & 0xffff0000u) * valB;
            aB[2] += __uint_as_float(uB.y << 16)         * valB;
            aB[3] += __uint_as_float(uB.y & 0xffff0000u) * valB;
            aB[4] += __uint_as_float(uB.z << 16)         * valB;
            aB[5] += __uint_as_float(uB.z & 0xffff0000u) * valB;
            aB[6] += __uint_as_float(uB.w << 16)         * valB;
            aB[7] += __uint_as_float(uB.w & 0xffff0000u) * valB;
        }
        #pragma unroll
        for (int k = 0; k < 8; ++k) {
            aA[k] += __shfl_xor(aA[k], 8);
            aA[k] += __shfl_xor(aA[k], 16);
            aA[k] += __shfl_xor(aA[k], 32);
            aB[k] += __shfl_xor(aB[k], 8);
            aB[k] += __shfl_xor(aB[k], 16);
            aB[k] += __shfl_xor(aB[k], 32);
        }
        if (lane < 8) {
            const uint4 oA = pack8_relu(aA);
            const uint4 oB = pack8_relu(aB);
            const int nodeA = b * 64 + nA;
            const int nodeB = b * 64 + nB;
            if (nodeA < N_NODES)
                *reinterpret_cast<uint4*>(&aggG[(size_t)nodeA * 32 + lane * 4]) = oA;
            if (nodeB < N_NODES)
                *reinterpret_cast<uint4*>(&aggG[(size_t)nodeB * 32 + lane * 4]) = oB;
        }
    }
}

// ---------------------------------------------------------------------------
// Gather pass 2 (dims 64-127, kept in LDS) + fused GEMM2 + row L2-norm.
// A-fragments: ks 0,1 from global aggG (pass-1 output), ks 2,3 from LDS.
// ---------------------------------------------------------------------------
__global__ __launch_bounds__(256) void gather_h1_gemm2(
    const unsigned int* __restrict__ sup, const int2* __restrict__ bucketed,
    const int* __restrict__ bcnt, const unsigned int* __restrict__ aggG,
    const short8* __restrict__ Bp, const float* __restrict__ bias,
    float* __restrict__ out)
{
    __shared__ int2 ebuf[EBUF_CAP];
    __shared__ unsigned int aggL[64 * 36];     // half rows (32 uints) + pad
    __shared__ int cnt[64];
    __shared__ int coff[64];
    __shared__ int cur[64];

    const int b = blockIdx.x;
    const int t = threadIdx.x;
    int nE = bcnt[b];
    if (nE > EBUF_CAP) nE = EBUF_CAP;
    const int base = b * BCAP;

    // ---- counting sort by dst&63 into ebuf ----
    if (t < 64) cnt[t] = 0;
    __syncthreads();
    for (int i = t; i < nE; i += 256)
        atomicAdd(&cnt[(bucketed[base + i].x >> 16) & 63], 1);
    __syncthreads();
    if (t < 64) coff[t] = cnt[t];
    __syncthreads();
    for (int off = 1; off < 64; off <<= 1) {
        int u = 0;
        if (t < 64 && t >= off) u = coff[t - off];
        __syncthreads();
        if (t < 64 && t >= off) coff[t] += u;
        __syncthreads();
    }
    if (t < 64) cur[t] = coff[t] - cnt[t];
    __syncthreads();
    for (int i = t; i < nE; i += 256) {
        const int2 e = bucketed[base + i];
        const int  n = (e.x >> 16) & 63;
        const int  p = atomicAdd(&cur[n], 1);
        ebuf[p] = e;
    }
    __syncthreads();

    // ---- gather dims 64-127 into aggL ----
    const int w = t >> 6, lane = t & 63;
    const int g = lane >> 3, dl = lane & 7;
    for (int j = 0; j < 8; ++j) {
        const int nA = w * 16 + j, nB = nA + 8;
        const int endA = cur[nA], cA = cnt[nA], begA = endA - cA;
        const int endB = cur[nB], cB = cnt[nB], begB = endB - cB;
        float aA[8] = {0.f,0.f,0.f,0.f,0.f,0.f,0.f,0.f};
        float aB[8] = {0.f,0.f,0.f,0.f,0.f,0.f,0.f,0.f};
        const int nI = max((cA + 7) >> 3, (cB + 7) >> 3);
        #pragma unroll 2
        for (int it = 0; it < nI; ++it) {
            const int iA = begA + it * 8 + g;
            const int iB = begB + it * 8 + g;
            const bool vA = iA < endA, vB = iB < endB;
            const int2 eA = ebuf[vA ? iA : 0];
            const int2 eB = ebuf[vB ? iB : 0];
            const float valA = vA ? __int_as_float(eA.y) : 0.f;
            const float valB = vB ? __int_as_float(eB.y) : 0.f;
            const int sA = vA ? (eA.x & 0xFFFF) : 0;
            const int sB = vB ? (eB.x & 0xFFFF) : 0;
            const uint4 uA = *reinterpret_cast<const uint4*>(&sup[(size_t)sA * 64 + 32 + dl * 4]);
            const uint4 uB = *reinterpret_cast<const uint4*>(&sup[(size_t)sB * 64 + 32 + dl * 4]);
            aA[0] += __uint_as_float(uA.x << 16)         * valA;
            aA[1] += __uint_as_float(uA.x & 0xffff0000u) * valA;
            aA[2] += __uint_as_float(uA.y << 16)         * valA;
            aA[3] += __uint_as_float(uA.y & 0xffff0000u) * valA;
            aA[4] += __uint_as_float(uA.z << 16)         * valA;
            aA[5] += __uint_as_float(uA.z & 0xffff0000u) * valA;
            aA[6] += __uint_as_float(uA.w << 16)         * valA;
            aA[7] += __uint_as_float(uA.w & 0xffff0000u) * valA;
            aB[0] += __uint_as_float(uB.x << 16)         * valB;
            aB[1] += __uint_as_float(uB.x & 0xffff0000u) * valB;
            aB[2] += __uint_as_float(uB.y << 16)         * valB;
            aB[3] += __uint_as_float(uB.y & 0xffff0000u) * valB;
            aB[4] += __uint_as_float(uB.z << 16)         * valB;
            aB[5] += __uint_as_float(uB.z & 0xffff0000u) * valB;
            aB[6] += __uint_as_float(uB.w << 16)         * valB;
            aB[7] += __uint_as_float(uB.w & 0xffff0000u) * valB;
        }
        #pragma unroll
        for (int k = 0; k < 8; ++k) {
            aA[k] += __shfl_xor(aA[k], 8);
            aA[k] += __shfl_xor(aA[k], 16);
            aA[k] += __shfl_xor(aA[k], 32);
            aB[k] += __shfl_xor(aB[k], 8);
            aB[k] += __shfl_xor(aB[k], 16);
            aB[k] += __shfl_xor(aB[k], 32);
        }
        if (lane < 8) {
            *reinterpret_cast<uint4*>(&aggL[nA * 36 + lane * 4]) = pack8_relu(aA);
            *reinterpret_cast<uint4*>(&aggL[nB * 36 + lane * 4]) = pack8_relu(aB);
        }
    }
    __syncthreads();

    // ---- GEMM2 + row L2-norm: wave w owns strip w (16 rows) ----
    const int row0 = b * 64 + w * 16;
    if (row0 >= N_NODES) return;               // bucket 781: waves 1-3 idle
    const int m = lane & 15;
    const int q = lane >> 4;
    const int grow = row0 + m;

    short8 a[4];
    #pragma unroll
    for (int ks = 0; ks < 2; ++ks) {
        const uint4 t4 = *reinterpret_cast<const uint4*>(&aggG[(size_t)grow * 32 + ks * 16 + q * 4]);
        a[ks] = *reinterpret_cast<const short8*>(&t4);
    }
    #pragma unroll
    for (int ks = 2; ks < 4; ++ks) {
        const uint4 t4 = *reinterpret_cast<const uint4*>(&aggL[(w * 16 + m) * 36 + (ks - 2) * 16 + q * 4]);
        a[ks] = *reinterpret_cast<const short8*>(&t4);
    }

    floatx4 acc[8];
    #pragma unroll
    for (int nt = 0; nt < 8; ++nt) { acc[nt][0]=0.f; acc[nt][1]=0.f; acc[nt][2]=0.f; acc[nt][3]=0.f; }

    #pragma unroll
    for (int ks = 0; ks < 4; ++ks) {
        #pragma unroll
        for (int nt = 0; nt < 8; ++nt) {
            const short8 bf = Bp[(ks * 8 + nt) * 64 + lane];
            acc[nt] = __builtin_amdgcn_mfma_f32_16x16x32_bf16(a[ks], bf, acc[nt], 0, 0, 0);
        }
    }

    #pragma unroll
    for (int nt = 0; nt < 8; ++nt) {
        const float bb = bias[nt * 16 + m];
        #pragma unroll
        for (int i = 0; i < 4; ++i) acc[nt][i] += bb;
    }

    float sq[4] = {0.f, 0.f, 0.f, 0.f};
    #pragma unroll
    for (int nt = 0; nt < 8; ++nt)
        #pragma unroll
        for (int i = 0; i < 4; ++i) sq[i] += acc[nt][i] * acc[nt][i];
    #pragma unroll
    for (int i = 0; i < 4; ++i) {
        #pragma unroll
        for (int mask = 1; mask < 16; mask <<= 1)
            sq[i] += __shfl_xor(sq[i], mask);
        sq[i] = 1.0f / sqrtf(sq[i]);
    }

    #pragma unroll
    for (int nt = 0; nt < 8; ++nt) {
        #pragma unroll
        for (int i = 0; i < 4; ++i) {
            const int r = row0 + q * 4 + i;
            out[(size_t)r * DIM + nt * 16 + m] = acc[nt][i] * sq[i];
        }
    }
}

// ---------------------------------------------------------------------------
extern "C" void kernel_launch(void* const* d_in, const int* in_sizes, int n_in,
                              void* d_out, int out_size, void* d_ws, size_t ws_size,
                              hipStream_t stream) {
    const float* x    = (const float*)d_in[0];
    const float* vals = (const float*)d_in[1];
    const float* W_gc = (const float*)d_in[2];
    const float* b_gc = (const float*)d_in[3];
    const float* W2   = (const float*)d_in[4];
    const float* b2   = (const float*)d_in[5];
    const int*   src  = (const int*)d_in[6];
    const int*   dst  = (const int*)d_in[7];

    float* out = (float*)d_out;

    // ws layout (16B-aligned)
    const size_t SUP_B = (size_t)SUP_ROWS * DIM * 2;     // 12,812,288 (bf16, +tail slack)
    const size_t BUK_B = (size_t)N_BKT * BCAP * 8;       // 9,609,216
    const size_t AGG_B = (size_t)SUP_ROWS * 64 * 2;      // 6,406,144 (bf16 dims 0-63)
    char* wsb = (char*)d_ws;
    unsigned short* support = (unsigned short*)wsb;
    int2* bucketed = (int2*)(wsb + SUP_B);
    unsigned int* aggG = (unsigned int*)(wsb + SUP_B + BUK_B);
    int*  bcnt     = (int*)(wsb + SUP_B + BUK_B + AGG_B);
    uint4* pw1     = (uint4*)(wsb + SUP_B + BUK_B + AGG_B + 4096);
    uint4* pw2     = (uint4*)(wsb + SUP_B + BUK_B + AGG_B + 4096 + 32768);

    // 1. pack W1/W2 fragments + zero bucket counters
    pre_pack<<<17, 256, 0, stream>>>(W_gc, W2, pw1, pw2, bcnt);

    // 2. bucket scatter (first: overlaps MFMA blocks) || GEMM1
    front<<<FRONT_BLOCKS, 256, 0, stream>>>(
        x, b_gc, src, dst, vals, pw1, support, bcnt, bucketed);

    // 3. gather pass 1: dims 0-63 -> global agg half (hot set 6.4 MB)
    gather_h0<<<N_BKT, 256, 0, stream>>>(
        (const unsigned int*)support, bucketed, bcnt, aggG);

    // 4. gather pass 2: dims 64-127 in LDS + fused GEMM2 + norm
    gather_h1_gemm2<<<N_BKT, 256, 0, stream>>>(
        (const unsigned int*)support, bucketed, bcnt, aggG,
        (const short8*)pw2, b2, out);
}